// Round 2
// 691.641 us; speedup vs baseline: 1.0399x; 1.0399x over previous
//
#include <hip/hip_runtime.h>
#include <math.h>

// ---------------------------------------------------------------------------
// Problem: N=8192 tokens, D=4096, E=8 experts, R=16, top_k=2. ALL fp32 in/out.
// out = x @ W^T + sum_{e in top2} 2*w_e * (x @ A[e]^T) @ B[e]^T
// Strategy: convert x,W,A,B to bf16 in ws; fold LoRA down-proj into the base
// GEMM as a K-extension (K = 4096 + 128), fp32 accumulate, fp32 out.
// k_main uses the 256x256 8-phase counted-vmcnt schedule (HK/m201 template):
//   - BK=64, 8 waves (512 thr), 128 KiB LDS double-buffer
//   - per phase: ds-read one C-quadrant's A-frags (B-frags read once at q0),
//     stage ONE half-tile (2 global_load_lds/wave), s_barrier,
//     lgkmcnt(0)+sched_barrier, setprio(1), 16 MFMA, setprio(0), s_barrier
//   - vmcnt(4) once per K-tile (phase q3), never 0 in the main loop
//   - staging runs ahead: A(k+1) at phases q0/q1, B(k+2) at q2/q3 (B of tile k
//     is fully consumed at q0, so its buffer is overwrite-safe from q2)
// LDS tiles use an XOR-8 swizzle (chunk ^= row&7) to kill ds_read_b128 bank
// conflicts; swizzle is applied in GLOBAL address space during staging since
// global_load_lds's LDS write pattern (base + lane*16B) is fixed.
// ---------------------------------------------------------------------------

#define NTOK 8192
#define DIM  4096
#define NEXP 8
#define RANK 16
#define KAUG (NEXP * RANK)   // 128
#define KSPLIT 4             // k_ax split-K factor
#define NKT  ((DIM + KAUG) / 64)   // 66 K-tiles in k_main

typedef __bf16 bf16x8 __attribute__((ext_vector_type(8)));
typedef float  f32x4  __attribute__((ext_vector_type(4)));

__device__ __forceinline__ unsigned short f2bf(float f) {
    union { float f; unsigned int u; } v;
    v.f = f;
    unsigned int u = v.u;
    return (unsigned short)((u + 0x7fffu + ((u >> 16) & 1u)) >> 16);
}

// ---------------------------------------------------------------------------
// Kernel 0: fp32 -> bf16 conversion (vectorized), used for W, A
// ---------------------------------------------------------------------------
__global__ __launch_bounds__(256) void k_cvt(
    const float4* __restrict__ in, ushort4* __restrict__ outv, int n4)
{
    int i = blockIdx.x * 256 + threadIdx.x;
    if (i < n4) {
        float4 v = in[i];
        outv[i] = make_ushort4(f2bf(v.x), f2bf(v.y), f2bf(v.z), f2bf(v.w));
    }
}

// ---------------------------------------------------------------------------
// Kernel 1: permute+convert B fp32 [E][D][R] -> Bt bf16 [D][E*R]
// ---------------------------------------------------------------------------
__global__ __launch_bounds__(256) void k_bt(
    const float* __restrict__ B, unsigned short* __restrict__ Bt)
{
    int idx = blockIdx.x * 256 + threadIdx.x;   // over DIM*KAUG = 524288
    int o = idx >> 7;
    int j = idx & 127;
    int e = j >> 4;
    int r = j & 15;
    Bt[idx] = f2bf(B[((size_t)e * DIM + o) * RANK + r]);
}

// ---------------------------------------------------------------------------
// Kernel 2: gate (fp32 logits + top-2 + softmax) FUSED with x fp32->bf16.
// One block per token. gate_out[n] = {(float)e0, (float)e1, w0, w1}
// ---------------------------------------------------------------------------
__global__ __launch_bounds__(256) void k_gate(
    const float* __restrict__ x,
    const float* __restrict__ gW,
    float4* __restrict__ gate_out,
    ushort4* __restrict__ xb4)                 // bf16 mirror of x
{
    __shared__ float xs[DIM];
    __shared__ float logits[NEXP];
    const int n = blockIdx.x;

    const float4* xr = (const float4*)(x + (size_t)n * DIM);
    ushort4* xw = xb4 + (size_t)n * (DIM / 4);
    for (int c = threadIdx.x; c < DIM / 4; c += 256) {
        float4 v = xr[c];
        xs[4 * c + 0] = v.x;
        xs[4 * c + 1] = v.y;
        xs[4 * c + 2] = v.z;
        xs[4 * c + 3] = v.w;
        xw[c] = make_ushort4(f2bf(v.x), f2bf(v.y), f2bf(v.z), f2bf(v.w));
    }
    __syncthreads();

    const int wave = threadIdx.x >> 6;
    const int lane = threadIdx.x & 63;
    for (int e = wave; e < NEXP; e += 4) {
        const float* g = gW + (size_t)e * DIM;
        float s = 0.f;
        for (int i = lane; i < DIM; i += 64) s += xs[i] * g[i];
        #pragma unroll
        for (int off = 32; off; off >>= 1) s += __shfl_down(s, off);
        if (lane == 0) logits[e] = s;
    }
    __syncthreads();

    if (threadIdx.x == 0) {
        int e0 = 0; float v0 = logits[0];
        #pragma unroll
        for (int e = 1; e < NEXP; ++e)
            if (logits[e] > v0) { v0 = logits[e]; e0 = e; }
        int e1 = -1; float v1 = -INFINITY;
        #pragma unroll
        for (int e = 0; e < NEXP; ++e)
            if (e != e0 && logits[e] > v1) { v1 = logits[e]; e1 = e; }
        float b = __expf(v1 - v0);          // softmax over [v0,v1], v0 >= v1
        float w0 = 1.f / (1.f + b);
        float w1 = 1.f - w0;
        gate_out[n] = make_float4((float)e0, (float)e1, w0, w1);
    }
}

// ---------------------------------------------------------------------------
// Shared GEMM machinery for k_ax: 128x128 block tile, BK=64, 4 waves (2x2),
// each wave 4x4 fragments of mfma_f32_16x16x32_bf16. global_load_lds staging.
// LDS tile: [128 rows][8 chunks of 8 bf16]; PHYSICAL chunk = logical ^ (row&7).
// ---------------------------------------------------------------------------
__device__ __forceinline__ void stage_lds(
    const unsigned short* gbase, int strideElems,
    unsigned short* ldsBase, int wave, int lane)
{
    const int l8 = lane >> 3;                    // row within 8-row chunk
    const int c8 = ((lane & 7) ^ l8) << 3;       // swizzled source column chunk
    #pragma unroll
    for (int q = 0; q < 4; ++q) {
        const int r = wave * 32 + q * 8;         // wave-uniform row base
        const unsigned short* gp = gbase + (size_t)(r + l8) * strideElems + c8;
        unsigned short* lp = ldsBase + r * 64;   // wave-uniform; HW adds lane*16B
        __builtin_amdgcn_global_load_lds(
            (const __attribute__((address_space(1))) void*)gp,
            (__attribute__((address_space(3))) void*)lp,
            16, 0, 0);
    }
}

__device__ __forceinline__ void mfma_step(
    const unsigned short* As, const unsigned short* Bs,
    int waveM, int waveN, int lane, f32x4 acc[4][4])
{
    const int quad = lane >> 4;
    const int l15  = lane & 15;
    const int x7   = l15 & 7;                    // row&7 for all fragment rows
    #pragma unroll
    for (int s = 0; s < 2; ++s) {
        const int chunk = (s << 2) | quad;       // logical k-chunk (ko>>3)
        const int po = ((chunk ^ x7) << 3);      // swizzled element offset
        bf16x8 af[4], bfv[4];
        #pragma unroll
        for (int i = 0; i < 4; ++i)
            af[i] = *(const bf16x8*)(As + (waveM * 64 + i * 16 + l15) * 64 + po);
        #pragma unroll
        for (int j = 0; j < 4; ++j)
            bfv[j] = *(const bf16x8*)(Bs + (waveN * 64 + j * 16 + l15) * 64 + po);
        #pragma unroll
        for (int i = 0; i < 4; ++i)
            #pragma unroll
            for (int j = 0; j < 4; ++j)
                acc[i][j] = __builtin_amdgcn_mfma_f32_16x16x32_bf16(
                    af[i], bfv[j], acc[i][j], 0, 0, 0);
    }
}

// ---------------------------------------------------------------------------
// Kernel 3: ax split-K GEMM. Grid (64 row-tiles, KSPLIT). Block (rb, ks)
// computes axPart[ks] rows [rb*128,+128) over K slice [ks*1024,+1024), fp32.
// ---------------------------------------------------------------------------
__global__ __launch_bounds__(256) void k_ax(
    const unsigned short* __restrict__ xb,
    const unsigned short* __restrict__ Ab,     // [128][4096] bf16
    float* __restrict__ axPart)                // [KSPLIT][8192][128] fp32
{
    __shared__ __align__(16) unsigned short As[128 * 64];
    __shared__ __align__(16) unsigned short Bs[128 * 64];
    const int tid  = threadIdx.x;
    const int wave = tid >> 6, lane = tid & 63;
    const int waveM = wave >> 1, waveN = wave & 1;
    const int rowBase = blockIdx.x * 128;
    const int ks = blockIdx.y;
    const int k0 = ks * (DIM / KSPLIT);

    f32x4 acc[4][4] = {};

    for (int it = 0; it < (DIM / KSPLIT) / 64; ++it) {
        stage_lds(xb + (size_t)rowBase * DIM + k0 + it * 64, DIM, As, wave, lane);
        stage_lds(Ab + (size_t)0 * DIM       + k0 + it * 64, DIM, Bs, wave, lane);
        __syncthreads();
        mfma_step(As, Bs, waveM, waveN, lane, acc);
        __syncthreads();
    }

    float* outp = axPart + (size_t)ks * NTOK * KAUG;
    const int quad = lane >> 4, l15 = lane & 15;
    #pragma unroll
    for (int i = 0; i < 4; ++i) {
        #pragma unroll
        for (int j = 0; j < 4; ++j) {
            const int gc = waveN * 64 + j * 16 + l15;   // 0..127
            #pragma unroll
            for (int t = 0; t < 4; ++t) {
                const int gr = rowBase + waveM * 64 + i * 16 + quad * 4 + t;
                outp[(size_t)gr * KAUG + gc] = acc[i][j][t];
            }
        }
    }
}

// ---------------------------------------------------------------------------
// Kernel 3b: sum split-K partials, apply gate weights, emit bf16 cB
// ---------------------------------------------------------------------------
__global__ __launch_bounds__(256) void k_scale(
    const float* __restrict__ axPart,
    const float4* __restrict__ gate_out,
    unsigned short* __restrict__ cB)
{
    int idx = blockIdx.x * 256 + threadIdx.x;   // over NTOK*KAUG
    int n = idx >> 7;
    int j = idx & 127;
    float s = 0.f;
    #pragma unroll
    for (int ks = 0; ks < KSPLIT; ++ks)
        s += axPart[(size_t)ks * NTOK * KAUG + idx];
    float4 g = gate_out[n];
    int e  = j >> 4;
    int e0 = (int)g.x;
    int e1 = (int)g.y;
    float scale = (e == e0) ? 2.f * g.z : (e == e1) ? 2.f * g.w : 0.f;
    cB[idx] = f2bf(scale * s);
}

// ---------------------------------------------------------------------------
// Kernel 4: main GEMM, 256x256 tile, 8-phase counted-vmcnt schedule.
// K = 4096 (xb,Wb) + 128 (cB,Bt) -> fp32 out [8192][4096]
// 8 waves (2M x 4N); per wave 128x64 output = 8x4 frags of 16x16.
// Phase q computes m-frags {2q,2q+1} x all 4 n-frags over full BK=64.
// ---------------------------------------------------------------------------
__global__ __launch_bounds__(512) void k_main(
    const unsigned short* __restrict__ xb,    // [8192][4096] bf16
    const unsigned short* __restrict__ Wb,    // [4096][4096] bf16
    const unsigned short* __restrict__ cB,    // [8192][128]  bf16
    const unsigned short* __restrict__ Bt,    // [4096][128]  bf16
    float* __restrict__ out)                  // [8192][4096] fp32
{
    __shared__ __align__(16) unsigned short sA[2][256 * 64];  // 2 x 32 KiB
    __shared__ __align__(16) unsigned short sB[2][256 * 64];  // 2 x 32 KiB

    const int tid  = threadIdx.x;
    const int wave = tid >> 6, lane = tid & 63;
    const int wm = wave >> 2, wn = wave & 3;         // 2 x 4 wave grid
    const int quad = lane >> 4, l15 = lane & 15;
    const int x7 = l15 & 7;                          // row&7 for frag rows

    // bijective XCD swizzle: 512 blocks, 64 consecutive per XCD
    // -> each XCD owns 4 row-panels (A locality in its private L2)
    const int bid = blockIdx.x;
    const int swz = (bid & 7) * 64 + (bid >> 3);
    const int rowBase = (swz >> 4) * 256;            // 32 row tiles
    const int colBase = (swz & 15) * 256;            // 16 col tiles

    const unsigned short* aMain = xb + (size_t)rowBase * DIM;
    const unsigned short* bMain = Wb + (size_t)colBase * DIM;
    const unsigned short* aLora = cB + (size_t)rowBase * KAUG;
    const unsigned short* bLora = Bt + (size_t)colBase * KAUG;

    const int l8 = lane >> 3;
    const int c8 = ((lane & 7) ^ l8) << 3;           // swizzled global chunk

    // stage ONE half-tile (128 rows) of A or B for K-tile t: 2 loads/wave
    auto stageT = [&](int t, int half, bool isA) {
        if (t >= NKT) return;                        // uniform branch
        unsigned short* ldsR = isA ? &sA[t & 1][0] : &sB[t & 1][0];
        const unsigned short* g;
        int stride;
        if (t < DIM / 64) { g = (isA ? aMain : bMain) + t * 64;              stride = DIM;  }
        else              { g = (isA ? aLora : bLora) + (t - DIM / 64) * 64; stride = KAUG; }
        #pragma unroll
        for (int qq = 0; qq < 2; ++qq) {
            const int r0 = half * 128 + qq * 64 + wave * 8;   // wave-uniform
            const unsigned short* gp = g + (size_t)(r0 + l8) * stride + c8;
            unsigned short* lp = ldsR + r0 * 64;
            __builtin_amdgcn_global_load_lds(
                (const __attribute__((address_space(1))) void*)gp,
                (__attribute__((address_space(3))) void*)lp,
                16, 0, 0);
        }
    };

    f32x4 acc[8][4] = {};

    // Prologue: A(0) h0,h1; B(0) h0,h1; B(1) h0,h1  (12 loads/wave)
    // vmcnt(4): A(0)+B(0) complete, B(1) (4 loads) still in flight.
    stageT(0, 0, true);  stageT(0, 1, true);
    stageT(0, 0, false); stageT(0, 1, false);
    stageT(1, 0, false); stageT(1, 1, false);
    asm volatile("s_waitcnt vmcnt(4)" ::: "memory");
    __builtin_amdgcn_s_barrier();

    // Main loop. Safety invariants (2 barriers/phase make these sound):
    //  - A(k+1) staged q0/q1 into buf[cur^1]: A(k-1) reads ended phase q3 of
    //    k-1, barrier crossed -> safe.
    //  - B(k+2) staged q2/q3 into buf[cur]: B(k) fully read at q0, barrier
    //    crossed -> safe.
    //  - vmcnt(4) at q3 leaves only B(k+2) (4 loads) in flight; everything
    //    older -- incl. A(k+1),B(k+1) -- retired before next q0 reads them.
    #pragma unroll 2
    for (int k = 0; k < NKT; ++k) {
        const unsigned short* At = &sA[k & 1][0];
        const unsigned short* Bl = &sB[k & 1][0];
        bf16x8 bFr[4][2];                            // live across all 4 phases
        #pragma unroll
        for (int q = 0; q < 4; ++q) {
            bf16x8 aFr[2][2];
            #pragma unroll
            for (int mi = 0; mi < 2; ++mi)
                #pragma unroll
                for (int ksl = 0; ksl < 2; ++ksl) {
                    const int r  = wm * 128 + (q * 2 + mi) * 16 + l15;
                    const int ch = ksl * 4 + quad;
                    aFr[mi][ksl] = *(const bf16x8*)(At + r * 64 + ((ch ^ x7) << 3));
                }
            if (q == 0) {
                #pragma unroll
                for (int nf = 0; nf < 4; ++nf)
                    #pragma unroll
                    for (int ksl = 0; ksl < 2; ++ksl) {
                        const int r  = wn * 64 + nf * 16 + l15;
                        const int ch = ksl * 4 + quad;
                        bFr[nf][ksl] = *(const bf16x8*)(Bl + r * 64 + ((ch ^ x7) << 3));
                    }
            }
            if      (q == 0) stageT(k + 1, 0, true);
            else if (q == 1) stageT(k + 1, 1, true);
            else if (q == 2) stageT(k + 2, 0, false);
            else             stageT(k + 2, 1, false);

            __builtin_amdgcn_s_barrier();
            asm volatile("s_waitcnt lgkmcnt(0)" ::: "memory");
            __builtin_amdgcn_sched_barrier(0);       // rule #18: pin MFMAs after wait
            __builtin_amdgcn_s_setprio(1);
            #pragma unroll
            for (int mi = 0; mi < 2; ++mi)
                #pragma unroll
                for (int nf = 0; nf < 4; ++nf)
                    #pragma unroll
                    for (int ksl = 0; ksl < 2; ++ksl)
                        acc[q * 2 + mi][nf] = __builtin_amdgcn_mfma_f32_16x16x32_bf16(
                            aFr[mi][ksl], bFr[nf][ksl], acc[q * 2 + mi][nf], 0, 0, 0);
            __builtin_amdgcn_s_setprio(0);
            __builtin_amdgcn_sched_barrier(0);       // keep MFMA cluster in-phase
            if (q == 3) {
                if (k == NKT - 2)
                    asm volatile("s_waitcnt vmcnt(0)" ::: "memory");  // tail: A(65) has no B(67) behind it
                else if (k < NKT - 2)
                    asm volatile("s_waitcnt vmcnt(4)" ::: "memory");  // counted, never 0
            }
            __builtin_amdgcn_s_barrier();
        }
    }

    // Epilogue: same C/D mapping as verified 128^2 kernel
    #pragma unroll
    for (int mf = 0; mf < 8; ++mf) {
        #pragma unroll
        for (int nf = 0; nf < 4; ++nf) {
            const int gc = colBase + wn * 64 + nf * 16 + l15;
            #pragma unroll
            for (int t = 0; t < 4; ++t) {
                const int gr = rowBase + wm * 128 + mf * 16 + quad * 4 + t;
                out[(size_t)gr * DIM + gc] = acc[mf][nf][t];
            }
        }
    }
}

// ---------------------------------------------------------------------------
extern "C" void kernel_launch(void* const* d_in, const int* in_sizes, int n_in,
                              void* d_out, int out_size, void* d_ws, size_t ws_size,
                              hipStream_t stream) {
    (void)in_sizes; (void)n_in; (void)out_size; (void)ws_size;

    const float* x  = (const float*)d_in[0];  // [8192][4096]
    const float* bW = (const float*)d_in[1];  // [4096][4096]
    const float* gW = (const float*)d_in[2];  // [8][4096]
    const float* A  = (const float*)d_in[3];  // [8][16][4096] = [128][4096]
    const float* B  = (const float*)d_in[4];  // [8][4096][16]
    // d_in[5] = top_k (always 2)
    float* out = (float*)d_out;

    // workspace layout (all regions fully rewritten every launch)
    char* ws = (char*)d_ws;
    float4*         gate_out = (float4*)ws;                         //   128 KiB
    unsigned short* xb = (unsigned short*)(ws + (1u << 17));        //    64 MiB
    unsigned short* Wb = xb + (size_t)NTOK * DIM;                   //    32 MiB
    unsigned short* Ab = Wb + (size_t)DIM * DIM;                    //     1 MiB
    unsigned short* Bt = Ab + (size_t)KAUG * DIM;                   //     1 MiB
    unsigned short* cB = Bt + (size_t)DIM * KAUG;                   //     2 MiB
    float*      axPart = (float*)(cB + (size_t)NTOK * KAUG);        //    16 MiB
                                                                    // ~116 MiB

    k_gate<<<NTOK, 256, 0, stream>>>(x, gW, gate_out, (ushort4*)xb);
    k_cvt <<<(DIM * DIM / 4 + 255) / 256, 256, 0, stream>>>(
        (const float4*)bW, (ushort4*)Wb, DIM * DIM / 4);
    k_cvt <<<(KAUG * DIM / 4 + 255) / 256, 256, 0, stream>>>(
        (const float4*)A, (ushort4*)Ab, KAUG * DIM / 4);
    k_bt  <<<(DIM * KAUG) / 256, 256, 0, stream>>>(B, Bt);
    k_ax  <<<dim3(NTOK / 128, KSPLIT), 256, 0, stream>>>(xb, Ab, axPart);
    k_scale<<<(NTOK * KAUG) / 256, 256, 0, stream>>>(axPart, gate_out, cB);
    k_main<<<dim3(512), dim3(512), 0, stream>>>(xb, Wb, cB, Bt, out);
}

// Round 3
// 583.371 us; speedup vs baseline: 1.2329x; 1.1856x over previous
//
#include <hip/hip_runtime.h>
#include <math.h>

// ---------------------------------------------------------------------------
// Problem: N=8192 tokens, D=4096, E=8 experts, R=16, top_k=2. ALL fp32 in/out.
// out = x @ W^T + sum_{e in top2} 2*w_e * (x @ A[e]^T) @ B[e]^T
// Strategy: convert x,W,A,B to bf16 in ws; fold LoRA down-proj into the base
// GEMM as a K-extension (K = 4096 + 128), fp32 accumulate, fp32 out.
// k_main uses the 256x256 8-phase counted-vmcnt schedule (HK/m201 template).
// Round-3 changes:
//  - k_main: col-major XCD slot ordering (each XCD's 32 concurrent blocks span
//    4 row x 8 col panels instead of 2 x 16 -> fewer compulsory L2 misses per
//    K-step; k_main is staging-delivery-bound at MfmaUtil 43%).
//  - k_main: early lgkmcnt(8) drain hint at q0 (12 ds_reads in that phase).
//  - k_gate: wave-per-token x4 rewrite (no LDS, no syncthreads, gW amortized).
//  - k_scale / k_bt: vectorized ushort4 writes (were 2 B/lane stores).
// ---------------------------------------------------------------------------

#define NTOK 8192
#define DIM  4096
#define NEXP 8
#define RANK 16
#define KAUG (NEXP * RANK)   // 128
#define KSPLIT 4             // k_ax split-K factor
#define NKT  ((DIM + KAUG) / 64)   // 66 K-tiles in k_main

typedef __bf16 bf16x8 __attribute__((ext_vector_type(8)));
typedef float  f32x4  __attribute__((ext_vector_type(4)));

__device__ __forceinline__ unsigned short f2bf(float f) {
    union { float f; unsigned int u; } v;
    v.f = f;
    unsigned int u = v.u;
    return (unsigned short)((u + 0x7fffu + ((u >> 16) & 1u)) >> 16);
}

// ---------------------------------------------------------------------------
// Kernel 0: fp32 -> bf16 conversion (vectorized), used for W, A
// ---------------------------------------------------------------------------
__global__ __launch_bounds__(256) void k_cvt(
    const float4* __restrict__ in, ushort4* __restrict__ outv, int n4)
{
    int i = blockIdx.x * 256 + threadIdx.x;
    if (i < n4) {
        float4 v = in[i];
        outv[i] = make_ushort4(f2bf(v.x), f2bf(v.y), f2bf(v.z), f2bf(v.w));
    }
}

// ---------------------------------------------------------------------------
// Kernel 1: permute+convert B fp32 [E][D][R] -> Bt bf16 [D][E*R], ushort4 I/O.
// Thread handles 4 consecutive outputs: same o, same e, r..r+3 contiguous.
// ---------------------------------------------------------------------------
__global__ __launch_bounds__(256) void k_bt(
    const float* __restrict__ B, ushort4* __restrict__ Bt4)
{
    int i4 = blockIdx.x * 256 + threadIdx.x;    // over DIM*KAUG/4 = 131072
    int idx = i4 * 4;
    int o = idx >> 7;
    int j = idx & 127;
    int e = j >> 4;
    int r = j & 15;                              // multiple of 4
    const float4 v = *(const float4*)(B + ((size_t)e * DIM + o) * RANK + r);
    Bt4[i4] = make_ushort4(f2bf(v.x), f2bf(v.y), f2bf(v.z), f2bf(v.w));
}

// ---------------------------------------------------------------------------
// Kernel 2: gate (fp32 logits + top-2 + softmax) FUSED with x fp32->bf16.
// Wave-per-token x4: each wave owns 4 tokens, streams 16 float4 chunks/lane,
// accumulates all 8 expert dots on the fly (gW read once per 4 tokens),
// butterfly-reduces, lanes 0-3 emit gate_out. No LDS, no __syncthreads.
// ---------------------------------------------------------------------------
__global__ __launch_bounds__(256) void k_gate(
    const float* __restrict__ x,
    const float* __restrict__ gW,
    float4* __restrict__ gate_out,
    ushort4* __restrict__ xb4)                 // bf16 mirror of x
{
    const int wave = threadIdx.x >> 6;
    const int lane = threadIdx.x & 63;
    const int n0 = blockIdx.x * 16 + wave * 4;  // 4 tokens per wave

    const float4* __restrict__ g4 = (const float4*)gW;   // [8][1024]
    const float4* xr0 = (const float4*)(x + (size_t)(n0 + 0) * DIM);
    const float4* xr1 = (const float4*)(x + (size_t)(n0 + 1) * DIM);
    const float4* xr2 = (const float4*)(x + (size_t)(n0 + 2) * DIM);
    const float4* xr3 = (const float4*)(x + (size_t)(n0 + 3) * DIM);
    ushort4* xw0 = xb4 + (size_t)(n0 + 0) * (DIM / 4);
    ushort4* xw1 = xb4 + (size_t)(n0 + 1) * (DIM / 4);
    ushort4* xw2 = xb4 + (size_t)(n0 + 2) * (DIM / 4);
    ushort4* xw3 = xb4 + (size_t)(n0 + 3) * (DIM / 4);

    float s[4][8];
    #pragma unroll
    for (int t = 0; t < 4; ++t)
        #pragma unroll
        for (int e = 0; e < 8; ++e) s[t][e] = 0.f;

    for (int j = 0; j < 16; ++j) {
        const int idx = j * 64 + lane;
        float4 v0 = xr0[idx];
        float4 v1 = xr1[idx];
        float4 v2 = xr2[idx];
        float4 v3 = xr3[idx];
        #pragma unroll
        for (int e = 0; e < 8; ++e) {
            const float4 g = g4[e * (DIM / 4) + idx];
            s[0][e] += v0.x * g.x + v0.y * g.y + v0.z * g.z + v0.w * g.w;
            s[1][e] += v1.x * g.x + v1.y * g.y + v1.z * g.z + v1.w * g.w;
            s[2][e] += v2.x * g.x + v2.y * g.y + v2.z * g.z + v2.w * g.w;
            s[3][e] += v3.x * g.x + v3.y * g.y + v3.z * g.z + v3.w * g.w;
        }
        xw0[idx] = make_ushort4(f2bf(v0.x), f2bf(v0.y), f2bf(v0.z), f2bf(v0.w));
        xw1[idx] = make_ushort4(f2bf(v1.x), f2bf(v1.y), f2bf(v1.z), f2bf(v1.w));
        xw2[idx] = make_ushort4(f2bf(v2.x), f2bf(v2.y), f2bf(v2.z), f2bf(v2.w));
        xw3[idx] = make_ushort4(f2bf(v3.x), f2bf(v3.y), f2bf(v3.z), f2bf(v3.w));
    }

    // butterfly: every lane ends with the full sum for all (t,e)
    #pragma unroll
    for (int t = 0; t < 4; ++t)
        #pragma unroll
        for (int e = 0; e < 8; ++e)
            #pragma unroll
            for (int off = 32; off; off >>= 1)
                s[t][e] += __shfl_xor(s[t][e], off);

    #pragma unroll
    for (int t = 0; t < 4; ++t) {
        if (lane == t) {
            int e0 = 0; float v0 = s[t][0];
            #pragma unroll
            for (int e = 1; e < 8; ++e)
                if (s[t][e] > v0) { v0 = s[t][e]; e0 = e; }
            int e1 = -1; float v1 = -INFINITY;
            #pragma unroll
            for (int e = 0; e < 8; ++e)
                if (e != e0 && s[t][e] > v1) { v1 = s[t][e]; e1 = e; }
            float b = __expf(v1 - v0);      // softmax over [v0,v1], v0 >= v1
            float w0 = 1.f / (1.f + b);
            float w1 = 1.f - w0;
            gate_out[n0 + t] = make_float4((float)e0, (float)e1, w0, w1);
        }
    }
}

// ---------------------------------------------------------------------------
// Shared GEMM machinery for k_ax: 128x128 block tile, BK=64, 4 waves (2x2),
// each wave 4x4 fragments of mfma_f32_16x16x32_bf16. global_load_lds staging.
// LDS tile: [128 rows][8 chunks of 8 bf16]; PHYSICAL chunk = logical ^ (row&7).
// ---------------------------------------------------------------------------
__device__ __forceinline__ void stage_lds(
    const unsigned short* gbase, int strideElems,
    unsigned short* ldsBase, int wave, int lane)
{
    const int l8 = lane >> 3;                    // row within 8-row chunk
    const int c8 = ((lane & 7) ^ l8) << 3;       // swizzled source column chunk
    #pragma unroll
    for (int q = 0; q < 4; ++q) {
        const int r = wave * 32 + q * 8;         // wave-uniform row base
        const unsigned short* gp = gbase + (size_t)(r + l8) * strideElems + c8;
        unsigned short* lp = ldsBase + r * 64;   // wave-uniform; HW adds lane*16B
        __builtin_amdgcn_global_load_lds(
            (const __attribute__((address_space(1))) void*)gp,
            (__attribute__((address_space(3))) void*)lp,
            16, 0, 0);
    }
}

__device__ __forceinline__ void mfma_step(
    const unsigned short* As, const unsigned short* Bs,
    int waveM, int waveN, int lane, f32x4 acc[4][4])
{
    const int quad = lane >> 4;
    const int l15  = lane & 15;
    const int x7   = l15 & 7;                    // row&7 for all fragment rows
    #pragma unroll
    for (int s = 0; s < 2; ++s) {
        const int chunk = (s << 2) | quad;       // logical k-chunk (ko>>3)
        const int po = ((chunk ^ x7) << 3);      // swizzled element offset
        bf16x8 af[4], bfv[4];
        #pragma unroll
        for (int i = 0; i < 4; ++i)
            af[i] = *(const bf16x8*)(As + (waveM * 64 + i * 16 + l15) * 64 + po);
        #pragma unroll
        for (int j = 0; j < 4; ++j)
            bfv[j] = *(const bf16x8*)(Bs + (waveN * 64 + j * 16 + l15) * 64 + po);
        #pragma unroll
        for (int i = 0; i < 4; ++i)
            #pragma unroll
            for (int j = 0; j < 4; ++j)
                acc[i][j] = __builtin_amdgcn_mfma_f32_16x16x32_bf16(
                    af[i], bfv[j], acc[i][j], 0, 0, 0);
    }
}

// ---------------------------------------------------------------------------
// Kernel 3: ax split-K GEMM. Grid (64 row-tiles, KSPLIT). Block (rb, ks)
// computes axPart[ks] rows [rb*128,+128) over K slice [ks*1024,+1024), fp32.
// ---------------------------------------------------------------------------
__global__ __launch_bounds__(256) void k_ax(
    const unsigned short* __restrict__ xb,
    const unsigned short* __restrict__ Ab,     // [128][4096] bf16
    float* __restrict__ axPart)                // [KSPLIT][8192][128] fp32
{
    __shared__ __align__(16) unsigned short As[128 * 64];
    __shared__ __align__(16) unsigned short Bs[128 * 64];
    const int tid  = threadIdx.x;
    const int wave = tid >> 6, lane = tid & 63;
    const int waveM = wave >> 1, waveN = wave & 1;
    const int rowBase = blockIdx.x * 128;
    const int ks = blockIdx.y;
    const int k0 = ks * (DIM / KSPLIT);

    f32x4 acc[4][4] = {};

    for (int it = 0; it < (DIM / KSPLIT) / 64; ++it) {
        stage_lds(xb + (size_t)rowBase * DIM + k0 + it * 64, DIM, As, wave, lane);
        stage_lds(Ab + (size_t)0 * DIM       + k0 + it * 64, DIM, Bs, wave, lane);
        __syncthreads();
        mfma_step(As, Bs, waveM, waveN, lane, acc);
        __syncthreads();
    }

    float* outp = axPart + (size_t)ks * NTOK * KAUG;
    const int quad = lane >> 4, l15 = lane & 15;
    #pragma unroll
    for (int i = 0; i < 4; ++i) {
        #pragma unroll
        for (int j = 0; j < 4; ++j) {
            const int gc = waveN * 64 + j * 16 + l15;   // 0..127
            #pragma unroll
            for (int t = 0; t < 4; ++t) {
                const int gr = rowBase + waveM * 64 + i * 16 + quad * 4 + t;
                outp[(size_t)gr * KAUG + gc] = acc[i][j][t];
            }
        }
    }
}

// ---------------------------------------------------------------------------
// Kernel 3b: sum split-K partials, apply gate weights, emit bf16 cB (ushort4)
// Thread handles 4 consecutive idx: same token n, same expert e.
// ---------------------------------------------------------------------------
__global__ __launch_bounds__(256) void k_scale(
    const float* __restrict__ axPart,
    const float4* __restrict__ gate_out,
    ushort4* __restrict__ cB4)
{
    int i4 = blockIdx.x * 256 + threadIdx.x;    // over NTOK*KAUG/4
    int idx = i4 * 4;
    int n = idx >> 7;
    int j = idx & 127;
    float4 s = make_float4(0.f, 0.f, 0.f, 0.f);
    #pragma unroll
    for (int ks = 0; ks < KSPLIT; ++ks) {
        const float4 v = *(const float4*)(axPart + (size_t)ks * NTOK * KAUG + idx);
        s.x += v.x; s.y += v.y; s.z += v.z; s.w += v.w;
    }
    float4 g = gate_out[n];
    int e  = j >> 4;                             // uniform across the 4 elems
    int e0 = (int)g.x;
    int e1 = (int)g.y;
    float scale = (e == e0) ? 2.f * g.z : (e == e1) ? 2.f * g.w : 0.f;
    cB4[i4] = make_ushort4(f2bf(scale * s.x), f2bf(scale * s.y),
                           f2bf(scale * s.z), f2bf(scale * s.w));
}

// ---------------------------------------------------------------------------
// Kernel 4: main GEMM, 256x256 tile, 8-phase counted-vmcnt schedule.
// K = 4096 (xb,Wb) + 128 (cB,Bt) -> fp32 out [8192][4096]
// 8 waves (2M x 4N); per wave 128x64 output = 8x4 frags of 16x16.
// Phase q computes m-frags {2q,2q+1} x all 4 n-frags over full BK=64.
// ---------------------------------------------------------------------------
__global__ __launch_bounds__(512) void k_main(
    const unsigned short* __restrict__ xb,    // [8192][4096] bf16
    const unsigned short* __restrict__ Wb,    // [4096][4096] bf16
    const unsigned short* __restrict__ cB,    // [8192][128]  bf16
    const unsigned short* __restrict__ Bt,    // [4096][128]  bf16
    float* __restrict__ out)                  // [8192][4096] fp32
{
    __shared__ __align__(16) unsigned short sA[2][256 * 64];  // 2 x 32 KiB
    __shared__ __align__(16) unsigned short sB[2][256 * 64];  // 2 x 32 KiB

    const int tid  = threadIdx.x;
    const int wave = tid >> 6, lane = tid & 63;
    const int wm = wave >> 2, wn = wave & 3;         // 2 x 4 wave grid
    const int quad = lane >> 4, l15 = lane & 15;
    const int x7 = l15 & 7;                          // row&7 for frag rows

    // bijective XCD swizzle, col-major within XCD: each XCD owns 4 row-panels;
    // its 32 concurrent blocks span 4 rows x 8 cols (A shared x8, B shared x4)
    // -> 12 compulsory panel-slices per K-step instead of 18.
    const int bid  = blockIdx.x;
    const int xcd  = bid & 7, slot = bid >> 3;       // slot in [0,64)
    const int rowBase = (xcd * 4 + (slot & 3)) * 256;
    const int colBase = (slot >> 2) * 256;

    const unsigned short* aMain = xb + (size_t)rowBase * DIM;
    const unsigned short* bMain = Wb + (size_t)colBase * DIM;
    const unsigned short* aLora = cB + (size_t)rowBase * KAUG;
    const unsigned short* bLora = Bt + (size_t)colBase * KAUG;

    const int l8 = lane >> 3;
    const int c8 = ((lane & 7) ^ l8) << 3;           // swizzled global chunk

    // stage ONE half-tile (128 rows) of A or B for K-tile t: 2 loads/wave
    auto stageT = [&](int t, int half, bool isA) {
        if (t >= NKT) return;                        // uniform branch
        unsigned short* ldsR = isA ? &sA[t & 1][0] : &sB[t & 1][0];
        const unsigned short* g;
        int stride;
        if (t < DIM / 64) { g = (isA ? aMain : bMain) + t * 64;              stride = DIM;  }
        else              { g = (isA ? aLora : bLora) + (t - DIM / 64) * 64; stride = KAUG; }
        #pragma unroll
        for (int qq = 0; qq < 2; ++qq) {
            const int r0 = half * 128 + qq * 64 + wave * 8;   // wave-uniform
            const unsigned short* gp = g + (size_t)(r0 + l8) * stride + c8;
            unsigned short* lp = ldsR + r0 * 64;
            __builtin_amdgcn_global_load_lds(
                (const __attribute__((address_space(1))) void*)gp,
                (__attribute__((address_space(3))) void*)lp,
                16, 0, 0);
        }
    };

    f32x4 acc[8][4] = {};

    // Prologue: A(0) h0,h1; B(0) h0,h1; B(1) h0,h1  (12 loads/wave)
    // vmcnt(4): A(0)+B(0) complete, B(1) (4 loads) still in flight.
    stageT(0, 0, true);  stageT(0, 1, true);
    stageT(0, 0, false); stageT(0, 1, false);
    stageT(1, 0, false); stageT(1, 1, false);
    asm volatile("s_waitcnt vmcnt(4)" ::: "memory");
    __builtin_amdgcn_s_barrier();

    // Main loop. Safety invariants (2 barriers/phase make these sound):
    //  - A(k+1) staged q0/q1 into buf[cur^1]: A(k-1) reads ended phase q3 of
    //    k-1, barrier crossed -> safe.
    //  - B(k+2) staged q2/q3 into buf[cur]: B(k) fully read at q0, barrier
    //    crossed -> safe.
    //  - vmcnt(4) at q3 leaves only B(k+2) (4 loads) in flight; everything
    //    older -- incl. A(k+1),B(k+1) -- retired before next q0 reads them.
    #pragma unroll 2
    for (int k = 0; k < NKT; ++k) {
        const unsigned short* At = &sA[k & 1][0];
        const unsigned short* Bl = &sB[k & 1][0];
        bf16x8 bFr[4][2];                            // live across all 4 phases
        #pragma unroll
        for (int q = 0; q < 4; ++q) {
            bf16x8 aFr[2][2];
            #pragma unroll
            for (int mi = 0; mi < 2; ++mi)
                #pragma unroll
                for (int ksl = 0; ksl < 2; ++ksl) {
                    const int r  = wm * 128 + (q * 2 + mi) * 16 + l15;
                    const int ch = ksl * 4 + quad;
                    aFr[mi][ksl] = *(const bf16x8*)(At + r * 64 + ((ch ^ x7) << 3));
                }
            if (q == 0) {
                #pragma unroll
                for (int nf = 0; nf < 4; ++nf)
                    #pragma unroll
                    for (int ksl = 0; ksl < 2; ++ksl) {
                        const int r  = wn * 64 + nf * 16 + l15;
                        const int ch = ksl * 4 + quad;
                        bFr[nf][ksl] = *(const bf16x8*)(Bl + r * 64 + ((ch ^ x7) << 3));
                    }
            }
            if      (q == 0) stageT(k + 1, 0, true);
            else if (q == 1) stageT(k + 1, 1, true);
            else if (q == 2) stageT(k + 2, 0, false);
            else             stageT(k + 2, 1, false);

            if (q == 0)                              // 12 ds_reads this phase:
                asm volatile("s_waitcnt lgkmcnt(8)" ::: "memory");  // early drain

            __builtin_amdgcn_s_barrier();
            asm volatile("s_waitcnt lgkmcnt(0)" ::: "memory");
            __builtin_amdgcn_sched_barrier(0);       // rule #18: pin MFMAs after wait
            __builtin_amdgcn_s_setprio(1);
            #pragma unroll
            for (int mi = 0; mi < 2; ++mi)
                #pragma unroll
                for (int nf = 0; nf < 4; ++nf)
                    #pragma unroll
                    for (int ksl = 0; ksl < 2; ++ksl)
                        acc[q * 2 + mi][nf] = __builtin_amdgcn_mfma_f32_16x16x32_bf16(
                            aFr[mi][ksl], bFr[nf][ksl], acc[q * 2 + mi][nf], 0, 0, 0);
            __builtin_amdgcn_s_setprio(0);
            __builtin_amdgcn_sched_barrier(0);       // keep MFMA cluster in-phase
            if (q == 3) {
                if (k == NKT - 2)
                    asm volatile("s_waitcnt vmcnt(0)" ::: "memory");  // tail: A(65) has no B(67) behind it
                else if (k < NKT - 2)
                    asm volatile("s_waitcnt vmcnt(4)" ::: "memory");  // counted, never 0
            }
            __builtin_amdgcn_s_barrier();
        }
    }

    // Epilogue: same C/D mapping as verified 128^2 kernel
    #pragma unroll
    for (int mf = 0; mf < 8; ++mf) {
        #pragma unroll
        for (int nf = 0; nf < 4; ++nf) {
            const int gc = colBase + wn * 64 + nf * 16 + l15;
            #pragma unroll
            for (int t = 0; t < 4; ++t) {
                const int gr = rowBase + wm * 128 + mf * 16 + quad * 4 + t;
                out[(size_t)gr * DIM + gc] = acc[mf][nf][t];
            }
        }
    }
}

// ---------------------------------------------------------------------------
extern "C" void kernel_launch(void* const* d_in, const int* in_sizes, int n_in,
                              void* d_out, int out_size, void* d_ws, size_t ws_size,
                              hipStream_t stream) {
    (void)in_sizes; (void)n_in; (void)out_size; (void)ws_size;

    const float* x  = (const float*)d_in[0];  // [8192][4096]
    const float* bW = (const float*)d_in[1];  // [4096][4096]
    const float* gW = (const float*)d_in[2];  // [8][4096]
    const float* A  = (const float*)d_in[3];  // [8][16][4096] = [128][4096]
    const float* B  = (const float*)d_in[4];  // [8][4096][16]
    // d_in[5] = top_k (always 2)
    float* out = (float*)d_out;

    // workspace layout (all regions fully rewritten every launch)
    char* ws = (char*)d_ws;
    float4*         gate_out = (float4*)ws;                         //   128 KiB
    unsigned short* xb = (unsigned short*)(ws + (1u << 17));        //    64 MiB
    unsigned short* Wb = xb + (size_t)NTOK * DIM;                   //    32 MiB
    unsigned short* Ab = Wb + (size_t)DIM * DIM;                    //     1 MiB
    unsigned short* Bt = Ab + (size_t)KAUG * DIM;                   //     1 MiB
    unsigned short* cB = Bt + (size_t)DIM * KAUG;                   //     2 MiB
    float*      axPart = (float*)(cB + (size_t)NTOK * KAUG);        //    16 MiB
                                                                    // ~116 MiB

    k_gate<<<NTOK / 16, 256, 0, stream>>>(x, gW, gate_out, (ushort4*)xb);
    k_cvt <<<(DIM * DIM / 4 + 255) / 256, 256, 0, stream>>>(
        (const float4*)bW, (ushort4*)Wb, DIM * DIM / 4);
    k_cvt <<<(KAUG * DIM / 4 + 255) / 256, 256, 0, stream>>>(
        (const float4*)A, (ushort4*)Ab, KAUG * DIM / 4);
    k_bt  <<<(DIM * KAUG / 4) / 256, 256, 0, stream>>>(B, (ushort4*)Bt);
    k_ax  <<<dim3(NTOK / 128, KSPLIT), 256, 0, stream>>>(xb, Ab, axPart);
    k_scale<<<(NTOK * KAUG / 4) / 256, 256, 0, stream>>>(
        axPart, gate_out, (ushort4*)cB);
    k_main<<<dim3(512), dim3(512), 0, stream>>>(xb, Wb, cB, Bt, out);
}